// Round 4
// baseline (904.015 us; speedup 1.0000x reference)
//
#include <hip/hip_runtime.h>
#include <hip/hip_bf16.h>

// ---------- constants ----------
#define S_ 1024
#define H_ 2048
#define NH_ 16
#define KVH_ 4
#define HD_ 128
#define IM_ 1408
#define ISH_ 5632
#define E_ 8

typedef __bf16 bf16x8 __attribute__((ext_vector_type(8)));
typedef float f32x4 __attribute__((ext_vector_type(4)));

typedef unsigned int __attribute__((address_space(1))) as1_u32;
typedef unsigned int __attribute__((address_space(3))) as3_u32;

__device__ __forceinline__ void gload16(const void* g, void* l) {
  __builtin_amdgcn_global_load_lds((const as1_u32*)g, (as3_u32*)l, 16, 0, 0);
}

__device__ __forceinline__ short f2bf(float f) {
  unsigned u = __float_as_uint(f);
  u = u + 0x7FFFu + ((u >> 16) & 1u);   // RTNE
  return (short)(u >> 16);
}

__device__ __forceinline__ f32x4 mfma16(bf16x8 a, bf16x8 b, f32x4 c) {
  return __builtin_amdgcn_mfma_f32_16x16x32_bf16(a, b, c, 0, 0, 0);
}

template<bool MAXOP>
__device__ __forceinline__ float block_reduce(float v, float* sbuf) {
  #pragma unroll
  for (int o = 32; o >= 1; o >>= 1) {
    float t = __shfl_down(v, o);
    v = MAXOP ? fmaxf(v, t) : (v + t);
  }
  int lane = threadIdx.x & 63, w = threadIdx.x >> 6;
  if (lane == 0) sbuf[w] = v;
  __syncthreads();
  float r = sbuf[0];
  #pragma unroll
  for (int i = 1; i < 4; i++) r = MAXOP ? fmaxf(r, sbuf[i]) : (r + sbuf[i]);
  __syncthreads();
  return r;
}

// ---------- transpose+convert: src fp32 [z][R][C] -> dst bf16 [z][C][R] ----------
__global__ __launch_bounds__(256) void transpose_k(const float* src, short* dst, int R, int C,
                                                   long long srcZ, long long dstZ) {
  __shared__ short tile[64][72];
  src += (long long)blockIdx.z * srcZ;
  dst += (long long)blockIdx.z * dstZ;
  const int r0 = blockIdx.y * 64, c0 = blockIdx.x * 64;
  const int t = threadIdx.x;
  const int tr = t >> 4, tc4 = (t & 15) * 4;
  #pragma unroll
  for (int i = 0; i < 4; i++) {
    int r = tr + i * 16;
    float4 v = *(const float4*)&src[(size_t)(r0 + r) * C + c0 + tc4];
    tile[tc4 + 0][r] = f2bf(v.x);
    tile[tc4 + 1][r] = f2bf(v.y);
    tile[tc4 + 2][r] = f2bf(v.z);
    tile[tc4 + 3][r] = f2bf(v.w);
  }
  __syncthreads();
  const int row = t >> 2, kc = (t & 3) * 16;
  #pragma unroll
  for (int j = 0; j < 2; j++) {
    int kcol = kc + j * 8;
    *(int4*)&dst[(size_t)(c0 + row) * R + r0 + kcol] = *(const int4*)&tile[row][kcol];
  }
}

// ---------- GEMM: A bf16 [M,K], B bf16 [N,K] (K-contig), 3-deep pipeline, split-K ----------
// blockIdx.x = M-tile (fastest -> consecutive blocks share B panel for L2 reuse)
// blockIdx.y = N-tile, blockIdx.z = z*ksplit + kchunk-index
// EPI 0: C fp32 = alpha*acc                          (plain store, ksplit==1 only)
// EPI 1: atomicAdd(C, alpha*acc)                     (split-K dense)
// EPI 3: expert: A row = list[off+m], atomicAdd(C[(off+m)*ldc+n], acc)
// EPI 4: expert: A row = off+m, atomicAdd(C[list[off+m]*ldc+n], scale[off+m]*acc)
// EPI 5: atomicAdd(C[m*ldc+n], scale[m]*acc)
struct GemmP {
  const short* A; long long strideA; int adiv; int lda;
  const short* B; long long strideB; int bdiv; int ldb;
  void* C; long long strideC; int cdiv; int ldc;
  const int* e_off; const int* e_cnt;
  const int* list; const float* scale;
  float alpha;
  int M, N, K;
  int cskip, ckb;
  int ksplit, kchunk;
};

template<int EPI>
__global__ __launch_bounds__(256) void gemm_bt(GemmP p) {
  constexpr int BM = 128, BN = 128, BK = 32;
  __shared__ __align__(16) short As[3][BM * BK];
  __shared__ __align__(16) short Bs[3][BN * BK];
  const int zz = blockIdx.z;
  const int zo = zz / p.ksplit;
  const int kc = zz - zo * p.ksplit;
  const int m0 = blockIdx.x * BM;
  const int n0 = blockIdx.y * BN;
  int off = 0, cnt = p.M;
  if constexpr (EPI == 3 || EPI == 4) {
    off = p.e_off[zo]; cnt = p.e_cnt[zo];
    if (m0 >= cnt) return;
  }
  if (p.cskip && n0 >= m0 + BM) return;
  int kend = p.ckb ? min(m0 + BM, p.K) : p.K;
  const int kbeg = kc * p.kchunk;
  kend = min(kend, kbeg + p.kchunk);
  if (kbeg >= kend) return;
  const int nsteps = (kend - kbeg) / BK;   // all K extents are multiples of 32

  const short* Ab = p.A + (long long)(zo / p.adiv) * p.strideA;
  const short* Bb = p.B + (long long)(zo / p.bdiv) * p.strideB;

  const int tid = threadIdx.x;
  const int lane = tid & 63, wid = tid >> 6;
  const int wr = wid >> 1, wc = wid & 1;
  const int kg = lane >> 4, li = lane & 15;

  const int srow = tid >> 2, scol = (tid & 3) * 8;
  const short* aSrc[2];
  const short* bSrc[2];
  #pragma unroll
  for (int c = 0; c < 2; c++) {
    int ra = srow + c * 64;
    int gr;
    if constexpr (EPI == 3)      { int rr = m0 + ra; if (rr >= cnt) rr = cnt - 1; gr = p.list[off + rr]; }
    else if constexpr (EPI == 4) { int rr = m0 + ra; if (rr >= cnt) rr = cnt - 1; gr = off + rr; }
    else                         gr = m0 + ra;
    aSrc[c] = Ab + (long long)gr * p.lda + scol;
    bSrc[c] = Bb + (long long)(n0 + ra) * p.ldb + scol;
  }

  // each call issues exactly 4 global_load_lds per thread
  auto stage = [&](int k0, int buf) {
    #pragma unroll
    for (int c = 0; c < 2; c++) {
      gload16(aSrc[c] + k0, &As[buf][tid * 8 + c * 2048]);
      gload16(bSrc[c] + k0, &Bs[buf][tid * 8 + c * 2048]);
    }
  };

  f32x4 acc[4][4];
  #pragma unroll
  for (int i = 0; i < 4; i++)
    #pragma unroll
    for (int j = 0; j < 4; j++) acc[i][j] = (f32x4){0.f, 0.f, 0.f, 0.f};

  // prologue: stage steps 0 and 1
  stage(kbeg, 0);
  if (nsteps > 1) {
    stage(kbeg + BK, 1);
    asm volatile("s_waitcnt vmcnt(4)\ns_barrier" ::: "memory");
  } else {
    asm volatile("s_waitcnt vmcnt(0)\ns_barrier" ::: "memory");
  }

  int cur = 0, nxt = 2;
  for (int i = 0; i < nsteps; i++) {
    const bool pf = (i + 2) < nsteps;
    if (pf) stage(kbeg + (i + 2) * BK, nxt);
    bf16x8 av[4], bv[4];
    #pragma unroll
    for (int mi = 0; mi < 4; mi++)
      av[mi] = *(const bf16x8*)&As[cur][(wr * 64 + mi * 16 + li) * BK + kg * 8];
    #pragma unroll
    for (int nj = 0; nj < 4; nj++)
      bv[nj] = *(const bf16x8*)&Bs[cur][(wc * 64 + nj * 16 + li) * BK + kg * 8];
    #pragma unroll
    for (int mi = 0; mi < 4; mi++)
      #pragma unroll
      for (int nj = 0; nj < 4; nj++)
        acc[mi][nj] = mfma16(av[mi], bv[nj], acc[mi][nj]);
    if (i + 1 < nsteps) {
      // wait: previous prefetch (4 loads) landed; keep newest 4 in flight
      if (pf) asm volatile("s_waitcnt vmcnt(4)\ns_barrier" ::: "memory");
      else    asm volatile("s_waitcnt vmcnt(0)\ns_barrier" ::: "memory");
    }
    cur = (cur == 2) ? 0 : cur + 1;
    nxt = (nxt == 2) ? 0 : nxt + 1;
  }

  const long long zc = (long long)(zo / p.cdiv) * p.strideC;
  #pragma unroll
  for (int mi = 0; mi < 4; mi++) {
    #pragma unroll
    for (int nj = 0; nj < 4; nj++) {
      #pragma unroll
      for (int r = 0; r < 4; r++) {
        int ml = wr * 64 + mi * 16 + kg * 4 + r;
        int nl2 = wc * 64 + nj * 16 + li;
        int mg = m0 + ml, ng = n0 + nl2;
        float v = acc[mi][nj][r] * p.alpha;
        if constexpr (EPI == 0) {
          float* C = (float*)p.C + zc;
          C[(long long)mg * p.ldc + ng] = v;
        } else if constexpr (EPI == 1) {
          float* C = (float*)p.C + zc;
          atomicAdd(&C[(long long)mg * p.ldc + ng], v);
        } else if constexpr (EPI == 3) {
          if (mg < cnt) {
            float* C = (float*)p.C;
            atomicAdd(&C[(long long)(off + mg) * p.ldc + ng], v);
          }
        } else if constexpr (EPI == 4) {
          if (mg < cnt) {
            float* C = (float*)p.C;
            int tok = p.list[off + mg];
            atomicAdd(&C[(long long)tok * p.ldc + ng], p.scale[off + mg] * v);
          }
        } else if constexpr (EPI == 5) {
          float* C = (float*)p.C;
          atomicAdd(&C[(long long)mg * p.ldc + ng], p.scale[mg] * v);
        }
      }
    }
  }
}

// ---------- aux kernels ----------
__global__ __launch_bounds__(256) void rope_table_k(const int* pos_ids, float* ct, float* st) {
  int i = blockIdx.x * 256 + threadIdx.x;          // 1024*64
  int p = i >> 6, f = i & 63;
  float pos = (float)pos_ids[p];
  float inv = powf(1.0e6f, -(float)f * (1.f / 64.f));
  float a = pos * inv;
  ct[i] = cosf(a); st[i] = sinf(a);
}

__global__ __launch_bounds__(256) void rmsnorm_k(const float* x, const float* w, short* o,
                                                 float* copy_out, float* rs_out) {
  __shared__ float sbuf[4];
  int t = blockIdx.x;
  const float* xr = x + (long long)t * H_;
  float ss = 0.f;
  for (int i = threadIdx.x; i < H_ / 4; i += 256) {
    float4 v = ((const float4*)xr)[i];
    ss += v.x * v.x + v.y * v.y + v.z * v.z + v.w * v.w;
  }
  ss = block_reduce<false>(ss, sbuf);
  float rs = rsqrtf(ss * (1.f / (float)H_) + 1e-6f);
  for (int i = threadIdx.x; i < H_; i += 256) {
    float xv = xr[i];
    o[(long long)t * H_ + i] = f2bf(xv * rs * w[i]);
    if (copy_out) copy_out[(long long)t * H_ + i] = xv;
  }
  if (rs_out && threadIdx.x == 0) rs_out[t] = rs;
}

__global__ __launch_bounds__(256) void bias_init_k(const float* qb, const float* kb,
                                                   const float* vb, float* qkv) {
  int i = blockIdx.x * 256 + threadIdx.x;          // 1024*3072
  int j = i & 3071;
  float b = (j < 2048) ? qb[j] : ((j < 2560) ? kb[j - 2048] : vb[j - 2560]);
  qkv[i] = b;
}

// RoPE from fused qkv fp32 [t, 3072] slice -> bf16 [t, width]
__global__ __launch_bounds__(256) void rope_apply_k(const float* src, short* dst, const float* ct,
                                                    const float* st, int srcoff, int width, int total) {
  int i = blockIdx.x * 256 + threadIdx.x;
  if (i >= total) return;
  int t = i / width, j = i - t * width;
  int d = j & 127, f = d & 63;
  float c = ct[t * 64 + f], s = st[t * 64 + f];
  const float* row = src + (long long)t * 3072 + srcoff;
  float xv = row[j];
  float ov = (d < 64) ? -row[j + 64] : row[j - 64];
  dst[i] = f2bf(xv * c + ov * s);
}

__global__ __launch_bounds__(256) void vtrans_k(const float* qkv, short* vt) {
  int i = blockIdx.x * 256 + threadIdx.x;          // kvh*131072 + d*1024 + s
  int kvh = i >> 17, rem = i & 131071;
  int d = rem >> 10, s_ = rem & 1023;
  vt[i] = f2bf(qkv[(long long)s_ * 3072 + 2560 + kvh * 128 + d]);
}

__global__ __launch_bounds__(256) void cvt_bf16_k(const float* src, short* dst, int total) {
  int i = blockIdx.x * 256 + threadIdx.x;
  if (i < total) dst[i] = f2bf(src[i]);
}

__global__ __launch_bounds__(256) void softmax_k(const float* sc, short* P) {
  __shared__ float sbuf[4];
  long long row = blockIdx.x;                      // h*1024+q
  int q = (int)(row & (S_ - 1));
  const float* sr = sc + row * S_;
  short* pr = P + row * S_;
  int L = q + 1;
  float mx = -3.4e38f;
  for (int i = threadIdx.x; i < L; i += 256) mx = fmaxf(mx, sr[i]);
  mx = block_reduce<true>(mx, sbuf);
  float s = 0.f;
  for (int i = threadIdx.x; i < L; i += 256) s += __expf(sr[i] - mx);
  s = block_reduce<false>(s, sbuf);
  float inv = 1.f / s;
  for (int i = threadIdx.x; i < S_; i += 256) {
    float pv = (i < L) ? __expf(sr[i] - mx) * inv : 0.f;
    pr[i] = f2bf(pv);
  }
}

__global__ void router_k(const float* h2, const float* rs, const float* w2,
                         const float* rw, const float* sgw,
                         int* top_i, float* top_w, float* sg_sig, int* counts) {
  int t = blockIdx.x;
  int l = threadIdx.x;   // 64 threads
  float le[8] = {0, 0, 0, 0, 0, 0, 0, 0};
  float ls = 0.f;
  float r = rs[t];
  for (int k = l; k < H_; k += 64) {
    float xv = h2[(long long)t * H_ + k] * r * w2[k];
    ls += xv * sgw[k];
    const float* rk = rw + k * E_;
    #pragma unroll
    for (int e = 0; e < E_; e++) le[e] += xv * rk[e];
  }
  #pragma unroll
  for (int o = 32; o >= 1; o >>= 1) {
    ls += __shfl_down(ls, o);
    #pragma unroll
    for (int e = 0; e < E_; e++) le[e] += __shfl_down(le[e], o);
  }
  if (l == 0) {
    float m = le[0];
    for (int e = 1; e < E_; e++) m = fmaxf(m, le[e]);
    float pe[8], s = 0.f;
    for (int e = 0; e < E_; e++) { pe[e] = __expf(le[e] - m); s += pe[e]; }
    float inv = 1.f / s;
    for (int e = 0; e < E_; e++) pe[e] *= inv;
    int i1 = 0;
    for (int e = 1; e < E_; e++) if (pe[e] > pe[i1]) i1 = e;
    int i2 = -1;
    for (int e = 0; e < E_; e++) if (e != i1 && (i2 < 0 || pe[e] > pe[i2])) i2 = e;
    top_i[2 * t] = i1; top_i[2 * t + 1] = i2;
    top_w[2 * t] = pe[i1]; top_w[2 * t + 1] = pe[i2];
    sg_sig[t] = 1.f / (1.f + __expf(-ls));
    atomicAdd(&counts[i1], 1); atomicAdd(&counts[i2], 1);
  }
}

__global__ void scan_k(const int* counts, int* offs) {
  if (threadIdx.x == 0 && blockIdx.x == 0) {
    int s = 0;
    for (int e = 0; e < E_; e++) { offs[e] = s; s += counts[e]; }
  }
}

__global__ __launch_bounds__(256) void fill_k(const int* top_i, const float* top_w, const int* offs,
                                              int* pos, int* list, float* pw) {
  int t = blockIdx.x * 256 + threadIdx.x;
  if (t >= S_) return;
  for (int j = 0; j < 2; j++) {
    int e = top_i[2 * t + j];
    int p_ = atomicAdd(&pos[e], 1);
    int slot = offs[e] + p_;
    list[slot] = t; pw[slot] = top_w[2 * t + j];
  }
}

// fused silu: src fp32 rows of [srcld], g at col j, u at col half+j -> dst bf16 [t*half+j]
__global__ __launch_bounds__(256) void silu_mul_k(const float* src, short* dst, int half,
                                                  int srcld, int total) {
  int i = blockIdx.x * 256 + threadIdx.x;
  if (i >= total) return;
  int t = i / half, j = i - t * half;
  const float* row = src + (long long)t * srcld;
  float g = row[j], u = row[half + j];
  float sig = 1.f / (1.f + __expf(-g));
  dst[i] = f2bf(g * sig * u);
}

// ---------- host ----------
static GemmP mkp() {
  GemmP p{};
  p.adiv = 1; p.bdiv = 1; p.cdiv = 1; p.alpha = 1.f;
  p.ksplit = 1; p.kchunk = 1 << 30;
  return p;
}

extern "C" void kernel_launch(void* const* d_in, const int* in_sizes, int n_in,
                              void* d_out, int out_size, void* d_ws, size_t ws_size,
                              hipStream_t stream) {
  const float* hidden   = (const float*)d_in[0];
  const int*   pos_ids  = (const int*)d_in[1];
  const float* ln1_w    = (const float*)d_in[2];
  const float* ln2_w    = (const float*)d_in[3];
  const float* q_w      = (const float*)d_in[4];
  const float* q_b      = (const float*)d_in[5];
  const float* k_w      = (const float*)d_in[6];
  const float* k_b      = (const float*)d_in[7];
  const float* v_w      = (const float*)d_in[8];
  const float* v_b      = (const float*)d_in[9];
  const float* o_w      = (const float*)d_in[10];
  const float* router_w = (const float*)d_in[11];
  const float* e_gate   = (const float*)d_in[12];
  const float* e_up     = (const float*)d_in[13];
  const float* e_down   = (const float*)d_in[14];
  const float* s_gate   = (const float*)d_in[15];
  const float* s_up     = (const float*)d_in[16];
  const float* s_down   = (const float*)d_in[17];
  const float* sg_w     = (const float*)d_in[18];
  float* out = (float*)d_out;

  char* base = (char*)d_ws;
  size_t off_ = 0;
  auto alc = [&](size_t nbytes) -> char* {
    off_ = (off_ + 255) & ~(size_t)255;
    char* p = base + off_;
    off_ += nbytes;
    return p;
  };
  // transposed bf16 weights
  short* qkvT = (short*)alc((size_t)3072 * H_ * 2);          // rows: q 0..2047, k 2048..2559, v 2560..3071
  short* oT   = (short*)alc((size_t)H_ * H_ * 2);
  short* eguT = (short*)alc((size_t)E_ * 2816 * H_ * 2);     // per expert: gate rows 0..1407, up 1408..2815
  short* edT  = (short*)alc((size_t)E_ * H_ * IM_ * 2);
  short* sguT = (short*)alc((size_t)11264 * H_ * 2);         // gate rows 0..5631, up 5632..11263
  short* sdT  = (short*)alc((size_t)H_ * ISH_ * 2);
  // activations
  short* x1      = (short*)alc((size_t)S_ * H_ * 2);
  float* qkv_f   = (float*)alc((size_t)S_ * 3072 * 4);
  float* ct      = (float*)alc((size_t)S_ * 64 * 4);
  float* st      = (float*)alc((size_t)S_ * 64 * 4);
  short* qr      = (short*)alc((size_t)S_ * H_ * 2);
  short* kr      = (short*)alc((size_t)S_ * 512 * 2);
  short* vt      = (short*)alc((size_t)S_ * 512 * 2);
  float* attn_f  = (float*)alc((size_t)S_ * H_ * 4);
  short* attn    = (short*)alc((size_t)S_ * H_ * 2);
  float* h2      = (float*)alc((size_t)S_ * H_ * 4);
  short* x2      = (short*)alc((size_t)S_ * H_ * 2);
  float* rs2     = (float*)alc(S_ * 4);
  int*   top_i   = (int*)alc(2 * S_ * 4);
  float* top_w   = (float*)alc(2 * S_ * 4);
  float* sg_sig  = (float*)alc(S_ * 4);
  int*   counts  = (int*)alc(64);
  int*   pos     = counts + 8;
  int*   offs    = (int*)alc(32);
  int*   list    = (int*)alc(2 * S_ * 4);
  float* pw      = (float*)alc(2 * S_ * 4);
  char*  region  = alc(100663296);   // 96 MiB overlay
  float* scores  = (float*)region;                            // 64 MiB
  short* P       = (short*)(region + 67108864);               // 32 MiB
  float* g_moeF  = (float*)region;                            // 2048x2816 fp32 = 23 MB
  short* gu_moeB = (short*)(region + 23068672);               // 2048x1408 bf16
  float* gushF   = (float*)(region + 28835840);               // 1024x11264 fp32 = 46 MB
  short* gushB   = (short*)(region + 74973184);               // 1024x5632 bf16

  // 0) weight transpose+convert
  transpose_k<<<dim3(32, 32, 1), 256, 0, stream>>>(q_w, qkvT, H_, H_, 0, 0);
  transpose_k<<<dim3(8, 32, 1), 256, 0, stream>>>(k_w, qkvT + (size_t)2048 * H_, H_, 512, 0, 0);
  transpose_k<<<dim3(8, 32, 1), 256, 0, stream>>>(v_w, qkvT + (size_t)2560 * H_, H_, 512, 0, 0);
  transpose_k<<<dim3(32, 32, 1), 256, 0, stream>>>(o_w, oT, H_, H_, 0, 0);
  transpose_k<<<dim3(22, 32, E_), 256, 0, stream>>>(e_gate, eguT, H_, IM_,
                                                    (long long)H_ * IM_, (long long)2816 * H_);
  transpose_k<<<dim3(22, 32, E_), 256, 0, stream>>>(e_up, eguT + (size_t)1408 * H_, H_, IM_,
                                                    (long long)H_ * IM_, (long long)2816 * H_);
  transpose_k<<<dim3(32, 22, E_), 256, 0, stream>>>(e_down, edT, IM_, H_,
                                                    (long long)IM_ * H_, (long long)IM_ * H_);
  transpose_k<<<dim3(88, 32, 1), 256, 0, stream>>>(s_gate, sguT, H_, ISH_, 0, 0);
  transpose_k<<<dim3(88, 32, 1), 256, 0, stream>>>(s_up, sguT + (size_t)5632 * H_, H_, ISH_, 0, 0);
  transpose_k<<<dim3(32, 88, 1), 256, 0, stream>>>(s_down, sdT, ISH_, H_, 0, 0);

  // 1) rope tables + rmsnorm1; h2 pre-init with residual
  rope_table_k<<<256, 256, 0, stream>>>(pos_ids, ct, st);
  rmsnorm_k<<<S_, 256, 0, stream>>>(hidden, ln1_w, x1, nullptr, nullptr);
  hipMemcpyAsync(h2, hidden, (size_t)S_ * H_ * 4, hipMemcpyDeviceToDevice, stream);
  hipMemsetAsync(attn_f, 0, (size_t)S_ * H_ * 4, stream);

  // 2) fused QKV projection (split-K=2, atomic into bias-initialized buffer)
  bias_init_k<<<12288, 256, 0, stream>>>(q_b, k_b, v_b, qkv_f);
  {
    GemmP p = mkp();
    p.A = x1; p.lda = H_;
    p.B = qkvT; p.ldb = H_;
    p.C = qkv_f; p.ldc = 3072;
    p.M = S_; p.N = 3072; p.K = H_;
    p.ksplit = 2; p.kchunk = 1024;
    gemm_bt<1><<<dim3(8, 24, 2), 256, 0, stream>>>(p);
  }

  // 3) RoPE + V transpose
  rope_apply_k<<<8192, 256, 0, stream>>>(qkv_f, qr, ct, st, 0, 2048, S_ * H_);
  rope_apply_k<<<2048, 256, 0, stream>>>(qkv_f, kr, ct, st, 2048, 512, S_ * 512);
  vtrans_k<<<2048, 256, 0, stream>>>(qkv_f, vt);

  // 4) scores = scale * Q K^T (causal tiles only)
  {
    GemmP p = mkp();
    p.A = qr; p.strideA = HD_; p.lda = H_;
    p.B = kr; p.strideB = HD_; p.bdiv = 4; p.ldb = 512;
    p.C = scores; p.strideC = (long long)S_ * S_; p.ldc = S_;
    p.alpha = 0.08838834764831845f;
    p.M = S_; p.N = S_; p.K = HD_; p.cskip = 1;
    p.kchunk = HD_;
    gemm_bt<0><<<dim3(8, 8, NH_), 256, 0, stream>>>(p);
  }
  softmax_k<<<NH_ * S_, 256, 0, stream>>>(scores, P);
  // 5) attn = P @ V  (split-K=4 over causal K, atomic into zeroed fp32)
  {
    GemmP p = mkp();
    p.A = P; p.strideA = (long long)S_ * S_; p.lda = S_;
    p.B = vt; p.strideB = (long long)HD_ * S_; p.bdiv = 4; p.ldb = S_;
    p.C = attn_f; p.strideC = HD_; p.ldc = H_;
    p.M = S_; p.N = HD_; p.K = S_; p.ckb = 1;
    p.ksplit = 4; p.kchunk = 256;
    gemm_bt<1><<<dim3(8, 1, NH_ * 4), 256, 0, stream>>>(p);
  }
  cvt_bf16_k<<<8192, 256, 0, stream>>>(attn_f, attn, S_ * H_);
  // 6) O-proj + residual -> h2 (pre-initialized with hidden), split-K=4
  {
    GemmP p = mkp();
    p.A = attn; p.lda = H_;
    p.B = oT; p.ldb = H_;
    p.C = h2; p.ldc = H_;
    p.M = S_; p.N = H_; p.K = H_;
    p.ksplit = 4; p.kchunk = 512;
    gemm_bt<1><<<dim3(8, 16, 4), 256, 0, stream>>>(p);
  }

  // 7) rmsnorm2 (x2 bf16; copy h2 -> d_out as accumulator base; save 1/rms)
  rmsnorm_k<<<S_, 256, 0, stream>>>(h2, ln2_w, x2, out, rs2);

  // 8) router / top-2 / gather lists
  hipMemsetAsync(counts, 0, 64, stream);
  router_k<<<S_, 64, 0, stream>>>(h2, rs2, ln2_w, router_w, sg_w, top_i, top_w, sg_sig, counts);
  scan_k<<<1, 1, 0, stream>>>(counts, offs);
  fill_k<<<4, 256, 0, stream>>>(top_i, top_w, offs, pos, list, pw);

  // 9) experts: fused gate+up (gathered, split-K=2), silu, down (scatter, split-K=2)
  hipMemsetAsync(g_moeF, 0, (size_t)2048 * 2816 * 4, stream);
  {
    GemmP p = mkp();
    p.A = x2; p.lda = H_;
    p.B = eguT; p.strideB = (long long)2816 * H_; p.ldb = H_;
    p.C = g_moeF; p.ldc = 2816;
    p.e_off = offs; p.e_cnt = counts; p.list = list;
    p.M = S_; p.N = 2816; p.K = H_;
    p.ksplit = 2; p.kchunk = 1024;
    gemm_bt<3><<<dim3(8, 22, E_ * 2), 256, 0, stream>>>(p);
  }
  silu_mul_k<<<11264, 256, 0, stream>>>(g_moeF, gu_moeB, IM_, 2816, 2048 * IM_);
  {
    GemmP p = mkp();
    p.A = gu_moeB; p.lda = IM_;
    p.B = edT; p.strideB = (long long)H_ * IM_; p.ldb = IM_;
    p.C = out; p.ldc = H_;
    p.e_off = offs; p.e_cnt = counts; p.list = list; p.scale = pw;
    p.M = S_; p.N = H_; p.K = IM_;
    p.ksplit = 2; p.kchunk = 704;
    gemm_bt<4><<<dim3(8, 16, E_ * 2), 256, 0, stream>>>(p);
  }

  // 10) shared expert: fused gate+up (704 blocks, plain store), silu, down (split-K=4)
  {
    GemmP p = mkp();
    p.A = x2; p.lda = H_;
    p.B = sguT; p.ldb = H_;
    p.C = gushF; p.ldc = 11264;
    p.M = S_; p.N = 11264; p.K = H_;
    p.kchunk = H_;
    gemm_bt<0><<<dim3(8, 88, 1), 256, 0, stream>>>(p);
  }
  silu_mul_k<<<22528, 256, 0, stream>>>(gushF, gushB, ISH_, 11264, S_ * ISH_);
  {
    GemmP p = mkp();
    p.A = gushB; p.lda = ISH_;
    p.B = sdT; p.ldb = ISH_;
    p.C = out; p.ldc = H_; p.scale = sg_sig;
    p.M = S_; p.N = H_; p.K = ISH_;
    p.ksplit = 4; p.kchunk = 1408;
    gemm_bt<5><<<dim3(8, 16, 4), 256, 0, stream>>>(p);
  }
}

// Round 5
// 836.361 us; speedup vs baseline: 1.0809x; 1.0809x over previous
//
#include <hip/hip_runtime.h>
#include <hip/hip_bf16.h>

// ---------- constants ----------
#define S_ 1024
#define H_ 2048
#define NH_ 16
#define KVH_ 4
#define HD_ 128
#define IM_ 1408
#define ISH_ 5632
#define E_ 8

typedef __bf16 bf16x8 __attribute__((ext_vector_type(8)));
typedef float f32x4 __attribute__((ext_vector_type(4)));

typedef unsigned int __attribute__((address_space(1))) as1_u32;
typedef unsigned int __attribute__((address_space(3))) as3_u32;

__device__ __forceinline__ void gload16(const void* g, void* l) {
  __builtin_amdgcn_global_load_lds((const as1_u32*)g, (as3_u32*)l, 16, 0, 0);
}

__device__ __forceinline__ short f2bf(float f) {
  unsigned u = __float_as_uint(f);
  u = u + 0x7FFFu + ((u >> 16) & 1u);   // RTNE
  return (short)(u >> 16);
}

__device__ __forceinline__ f32x4 mfma16(bf16x8 a, bf16x8 b, f32x4 c) {
  return __builtin_amdgcn_mfma_f32_16x16x32_bf16(a, b, c, 0, 0, 0);
}

template<bool MAXOP>
__device__ __forceinline__ float block_reduce(float v, float* sbuf) {
  #pragma unroll
  for (int o = 32; o >= 1; o >>= 1) {
    float t = __shfl_down(v, o);
    v = MAXOP ? fmaxf(v, t) : (v + t);
  }
  int lane = threadIdx.x & 63, w = threadIdx.x >> 6;
  if (lane == 0) sbuf[w] = v;
  __syncthreads();
  float r = sbuf[0];
  #pragma unroll
  for (int i = 1; i < 4; i++) r = MAXOP ? fmaxf(r, sbuf[i]) : (r + sbuf[i]);
  __syncthreads();
  return r;
}

// ---------- transpose+convert: src fp32 [z][R][C] -> dst bf16 [z][C][R] ----------
__global__ __launch_bounds__(256) void transpose_k(const float* src, short* dst, int R, int C,
                                                   long long srcZ, long long dstZ) {
  __shared__ short tile[64][72];
  src += (long long)blockIdx.z * srcZ;
  dst += (long long)blockIdx.z * dstZ;
  const int r0 = blockIdx.y * 64, c0 = blockIdx.x * 64;
  const int t = threadIdx.x;
  const int tr = t >> 4, tc4 = (t & 15) * 4;
  #pragma unroll
  for (int i = 0; i < 4; i++) {
    int r = tr + i * 16;
    float4 v = *(const float4*)&src[(size_t)(r0 + r) * C + c0 + tc4];
    tile[tc4 + 0][r] = f2bf(v.x);
    tile[tc4 + 1][r] = f2bf(v.y);
    tile[tc4 + 2][r] = f2bf(v.z);
    tile[tc4 + 3][r] = f2bf(v.w);
  }
  __syncthreads();
  const int row = t >> 2, kc = (t & 3) * 16;
  #pragma unroll
  for (int j = 0; j < 2; j++) {
    int kcol = kc + j * 8;
    *(int4*)&dst[(size_t)(c0 + row) * R + r0 + kcol] = *(const int4*)&tile[row][kcol];
  }
}

// ---------- GEMM: A bf16 [M,K], B bf16 [N,K] (K-contig), 2-phase dbuf, split-K ----------
// grid: x = M-tile, y = N-tile, z = zo*ksplit + kchunk-index.
// When Ntiles%8==0, (mt,nt) are decoded from a swizzled linear id so that all
// M-tile blocks of one N-tile land on the SAME XCD (lin%8 fixed per nt) ->
// the B weight panel stays in that XCD's L2 across all 8 M-tiles.
// EPI 0: C fp32 = alpha*acc                          (plain store, ksplit==1 only)
// EPI 1: atomicAdd(C, alpha*acc)                     (split-K dense)
// EPI 3: expert: A row = list[off+m], atomicAdd(C[(off+m)*ldc+n], acc)
// EPI 4: expert: A row = off+m, atomicAdd(C[list[off+m]*ldc+n], scale[off+m]*acc)
// EPI 5: atomicAdd(C[m*ldc+n], scale[m]*acc)
struct GemmP {
  const short* A; long long strideA; int adiv; int lda;
  const short* B; long long strideB; int bdiv; int ldb;
  void* C; long long strideC; int cdiv; int ldc;
  const int* e_off; const int* e_cnt;
  const int* list; const float* scale;
  float alpha;
  int M, N, K;
  int cskip, ckb;
  int ksplit, kchunk;
};

template<int EPI>
__global__ __launch_bounds__(256) void gemm_bt(GemmP p) {
  constexpr int BM = 128, BN = 128, BK = 32;
  __shared__ __align__(16) short As[2][BM * BK];
  __shared__ __align__(16) short Bs[2][BN * BK];
  const int zz = blockIdx.z;
  const int zo = zz / p.ksplit;
  const int kc = zz - zo * p.ksplit;

  // ---- XCD-affinity decode (bijective when gridDim.y % 8 == 0)
  int mt, nt;
  {
    const int Mt = gridDim.x, Nt = gridDim.y;
    if ((Nt & 7) == 0) {
      int lin = blockIdx.x + Mt * blockIdx.y;
      int r = lin & 7, q = lin >> 3;
      mt = q % Mt;
      nt = (q / Mt) * 8 + r;
    } else {
      mt = blockIdx.x; nt = blockIdx.y;
    }
  }
  const int m0 = mt * BM;
  const int n0 = nt * BN;

  int off = 0, cnt = p.M;
  if constexpr (EPI == 3 || EPI == 4) {
    off = p.e_off[zo]; cnt = p.e_cnt[zo];
    if (m0 >= cnt) return;
  }
  if (p.cskip && n0 >= m0 + BM) return;
  int kend = p.ckb ? min(m0 + BM, p.K) : p.K;
  const int kbeg = kc * p.kchunk;
  kend = min(kend, kbeg + p.kchunk);
  if (kbeg >= kend) return;

  const short* Ab = p.A + (long long)(zo / p.adiv) * p.strideA;
  const short* Bb = p.B + (long long)(zo / p.bdiv) * p.strideB;

  const int tid = threadIdx.x;
  const int lane = tid & 63, wid = tid >> 6;
  const int wr = wid >> 1, wc = wid & 1;
  const int kg = lane >> 4, li = lane & 15;

  const int srow = tid >> 2, scol = (tid & 3) * 8;
  const short* aSrc[2];
  const short* bSrc[2];
  #pragma unroll
  for (int c = 0; c < 2; c++) {
    int ra = srow + c * 64;
    int gr;
    if constexpr (EPI == 3)      { int rr = m0 + ra; if (rr >= cnt) rr = cnt - 1; gr = p.list[off + rr]; }
    else if constexpr (EPI == 4) { int rr = m0 + ra; if (rr >= cnt) rr = cnt - 1; gr = off + rr; }
    else                         gr = m0 + ra;
    aSrc[c] = Ab + (long long)gr * p.lda + scol;
    bSrc[c] = Bb + (long long)(n0 + ra) * p.ldb + scol;
  }

  f32x4 acc[4][4];
  #pragma unroll
  for (int i = 0; i < 4; i++)
    #pragma unroll
    for (int j = 0; j < 4; j++) acc[i][j] = (f32x4){0.f, 0.f, 0.f, 0.f};

  // prologue: stage first tile into buf 0
  #pragma unroll
  for (int c = 0; c < 2; c++) {
    gload16(aSrc[c] + kbeg, &As[0][tid * 8 + c * 2048]);
    gload16(bSrc[c] + kbeg, &Bs[0][tid * 8 + c * 2048]);
  }
  __syncthreads();

  int cur = 0;
  for (int k0 = kbeg; k0 < kend; k0 += BK) {
    // issue next-tile loads into the other buffer
    const int nk = k0 + BK;
    if (nk < kend) {
      #pragma unroll
      for (int c = 0; c < 2; c++) {
        gload16(aSrc[c] + nk, &As[cur ^ 1][tid * 8 + c * 2048]);
        gload16(bSrc[c] + nk, &Bs[cur ^ 1][tid * 8 + c * 2048]);
      }
    }
    bf16x8 av[4], bv[4];
    #pragma unroll
    for (int mi = 0; mi < 4; mi++)
      av[mi] = *(const bf16x8*)&As[cur][(wr * 64 + mi * 16 + li) * BK + kg * 8];
    #pragma unroll
    for (int nj = 0; nj < 4; nj++)
      bv[nj] = *(const bf16x8*)&Bs[cur][(wc * 64 + nj * 16 + li) * BK + kg * 8];
    #pragma unroll
    for (int mi = 0; mi < 4; mi++)
      #pragma unroll
      for (int nj = 0; nj < 4; nj++)
        acc[mi][nj] = mfma16(av[mi], bv[nj], acc[mi][nj]);
    __syncthreads();   // drains vmcnt (next tile landed) + orders LDS reuse
    cur ^= 1;
  }

  const long long zc = (long long)(zo / p.cdiv) * p.strideC;
  #pragma unroll
  for (int mi = 0; mi < 4; mi++) {
    #pragma unroll
    for (int nj = 0; nj < 4; nj++) {
      #pragma unroll
      for (int r = 0; r < 4; r++) {
        int ml = wr * 64 + mi * 16 + kg * 4 + r;
        int nl2 = wc * 64 + nj * 16 + li;
        int mg = m0 + ml, ng = n0 + nl2;
        float v = acc[mi][nj][r] * p.alpha;
        if constexpr (EPI == 0) {
          float* C = (float*)p.C + zc;
          C[(long long)mg * p.ldc + ng] = v;
        } else if constexpr (EPI == 1) {
          float* C = (float*)p.C + zc;
          atomicAdd(&C[(long long)mg * p.ldc + ng], v);
        } else if constexpr (EPI == 3) {
          if (mg < cnt) {
            float* C = (float*)p.C;
            atomicAdd(&C[(long long)(off + mg) * p.ldc + ng], v);
          }
        } else if constexpr (EPI == 4) {
          if (mg < cnt) {
            float* C = (float*)p.C;
            int tok = p.list[off + mg];
            atomicAdd(&C[(long long)tok * p.ldc + ng], p.scale[off + mg] * v);
          }
        } else if constexpr (EPI == 5) {
          float* C = (float*)p.C;
          atomicAdd(&C[(long long)mg * p.ldc + ng], p.scale[mg] * v);
        }
      }
    }
  }
}

// ---------- aux kernels ----------
__global__ __launch_bounds__(256) void rope_table_k(const int* pos_ids, float* ct, float* st) {
  int i = blockIdx.x * 256 + threadIdx.x;          // 1024*64
  int p = i >> 6, f = i & 63;
  float pos = (float)pos_ids[p];
  float inv = powf(1.0e6f, -(float)f * (1.f / 64.f));
  float a = pos * inv;
  ct[i] = cosf(a); st[i] = sinf(a);
}

__global__ __launch_bounds__(256) void rmsnorm_k(const float* x, const float* w, short* o,
                                                 float* copy_out, float* rs_out) {
  __shared__ float sbuf[4];
  int t = blockIdx.x;
  const float* xr = x + (long long)t * H_;
  float ss = 0.f;
  for (int i = threadIdx.x; i < H_ / 4; i += 256) {
    float4 v = ((const float4*)xr)[i];
    ss += v.x * v.x + v.y * v.y + v.z * v.z + v.w * v.w;
  }
  ss = block_reduce<false>(ss, sbuf);
  float rs = rsqrtf(ss * (1.f / (float)H_) + 1e-6f);
  for (int i = threadIdx.x; i < H_; i += 256) {
    float xv = xr[i];
    o[(long long)t * H_ + i] = f2bf(xv * rs * w[i]);
    if (copy_out) copy_out[(long long)t * H_ + i] = xv;
  }
  if (rs_out && threadIdx.x == 0) rs_out[t] = rs;
}

__global__ __launch_bounds__(256) void bias_init_k(const float* qb, const float* kb,
                                                   const float* vb, float* qkv) {
  int i = blockIdx.x * 256 + threadIdx.x;          // 1024*3072
  int j = i & 3071;
  float b = (j < 2048) ? qb[j] : ((j < 2560) ? kb[j - 2048] : vb[j - 2560]);
  qkv[i] = b;
}

// RoPE from fused qkv fp32 [t, 3072] slice -> bf16 [t, width]
__global__ __launch_bounds__(256) void rope_apply_k(const float* src, short* dst, const float* ct,
                                                    const float* st, int srcoff, int width, int total) {
  int i = blockIdx.x * 256 + threadIdx.x;
  if (i >= total) return;
  int t = i / width, j = i - t * width;
  int d = j & 127, f = d & 63;
  float c = ct[t * 64 + f], s = st[t * 64 + f];
  const float* row = src + (long long)t * 3072 + srcoff;
  float xv = row[j];
  float ov = (d < 64) ? -row[j + 64] : row[j - 64];
  dst[i] = f2bf(xv * c + ov * s);
}

__global__ __launch_bounds__(256) void vtrans_k(const float* qkv, short* vt) {
  int i = blockIdx.x * 256 + threadIdx.x;          // kvh*131072 + d*1024 + s
  int kvh = i >> 17, rem = i & 131071;
  int d = rem >> 10, s_ = rem & 1023;
  vt[i] = f2bf(qkv[(long long)s_ * 3072 + 2560 + kvh * 128 + d]);
}

__global__ __launch_bounds__(256) void cvt_bf16_k(const float* src, short* dst, int total) {
  int i = blockIdx.x * 256 + threadIdx.x;
  if (i < total) dst[i] = f2bf(src[i]);
}

__global__ __launch_bounds__(256) void softmax_k(const float* sc, short* P) {
  __shared__ float sbuf[4];
  long long row = blockIdx.x;                      // h*1024+q
  int q = (int)(row & (S_ - 1));
  const float* sr = sc + row * S_;
  short* pr = P + row * S_;
  int L = q + 1;
  float mx = -3.4e38f;
  for (int i = threadIdx.x; i < L; i += 256) mx = fmaxf(mx, sr[i]);
  mx = block_reduce<true>(mx, sbuf);
  float s = 0.f;
  for (int i = threadIdx.x; i < L; i += 256) s += __expf(sr[i] - mx);
  s = block_reduce<false>(s, sbuf);
  float inv = 1.f / s;
  for (int i = threadIdx.x; i < S_; i += 256) {
    float pv = (i < L) ? __expf(sr[i] - mx) * inv : 0.f;
    pr[i] = f2bf(pv);
  }
}

__global__ void router_k(const float* h2, const float* rs, const float* w2,
                         const float* rw, const float* sgw,
                         int* top_i, float* top_w, float* sg_sig, int* counts) {
  int t = blockIdx.x;
  int l = threadIdx.x;   // 64 threads
  float le[8] = {0, 0, 0, 0, 0, 0, 0, 0};
  float ls = 0.f;
  float r = rs[t];
  for (int k = l; k < H_; k += 64) {
    float xv = h2[(long long)t * H_ + k] * r * w2[k];
    ls += xv * sgw[k];
    const float* rk = rw + k * E_;
    #pragma unroll
    for (int e = 0; e < E_; e++) le[e] += xv * rk[e];
  }
  #pragma unroll
  for (int o = 32; o >= 1; o >>= 1) {
    ls += __shfl_down(ls, o);
    #pragma unroll
    for (int e = 0; e < E_; e++) le[e] += __shfl_down(le[e], o);
  }
  if (l == 0) {
    float m = le[0];
    for (int e = 1; e < E_; e++) m = fmaxf(m, le[e]);
    float pe[8], s = 0.f;
    for (int e = 0; e < E_; e++) { pe[e] = __expf(le[e] - m); s += pe[e]; }
    float inv = 1.f / s;
    for (int e = 0; e < E_; e++) pe[e] *= inv;
    int i1 = 0;
    for (int e = 1; e < E_; e++) if (pe[e] > pe[i1]) i1 = e;
    int i2 = -1;
    for (int e = 0; e < E_; e++) if (e != i1 && (i2 < 0 || pe[e] > pe[i2])) i2 = e;
    top_i[2 * t] = i1; top_i[2 * t + 1] = i2;
    top_w[2 * t] = pe[i1]; top_w[2 * t + 1] = pe[i2];
    sg_sig[t] = 1.f / (1.f + __expf(-ls));
    atomicAdd(&counts[i1], 1); atomicAdd(&counts[i2], 1);
  }
}

__global__ void scan_k(const int* counts, int* offs) {
  if (threadIdx.x == 0 && blockIdx.x == 0) {
    int s = 0;
    for (int e = 0; e < E_; e++) { offs[e] = s; s += counts[e]; }
  }
}

__global__ __launch_bounds__(256) void fill_k(const int* top_i, const float* top_w, const int* offs,
                                              int* pos, int* list, float* pw) {
  int t = blockIdx.x * 256 + threadIdx.x;
  if (t >= S_) return;
  for (int j = 0; j < 2; j++) {
    int e = top_i[2 * t + j];
    int p_ = atomicAdd(&pos[e], 1);
    int slot = offs[e] + p_;
    list[slot] = t; pw[slot] = top_w[2 * t + j];
  }
}

// fused silu: src fp32 rows of [srcld], g at col j, u at col half+j -> dst bf16 [t*half+j]
__global__ __launch_bounds__(256) void silu_mul_k(const float* src, short* dst, int half,
                                                  int srcld, int total) {
  int i = blockIdx.x * 256 + threadIdx.x;
  if (i >= total) return;
  int t = i / half, j = i - t * half;
  const float* row = src + (long long)t * srcld;
  float g = row[j], u = row[half + j];
  float sig = 1.f / (1.f + __expf(-g));
  dst[i] = f2bf(g * sig * u);
}

// ---------- host ----------
static GemmP mkp() {
  GemmP p{};
  p.adiv = 1; p.bdiv = 1; p.cdiv = 1; p.alpha = 1.f;
  p.ksplit = 1; p.kchunk = 1 << 30;
  return p;
}

extern "C" void kernel_launch(void* const* d_in, const int* in_sizes, int n_in,
                              void* d_out, int out_size, void* d_ws, size_t ws_size,
                              hipStream_t stream) {
  const float* hidden   = (const float*)d_in[0];
  const int*   pos_ids  = (const int*)d_in[1];
  const float* ln1_w    = (const float*)d_in[2];
  const float* ln2_w    = (const float*)d_in[3];
  const float* q_w      = (const float*)d_in[4];
  const float* q_b      = (const float*)d_in[5];
  const float* k_w      = (const float*)d_in[6];
  const float* k_b      = (const float*)d_in[7];
  const float* v_w      = (const float*)d_in[8];
  const float* v_b      = (const float*)d_in[9];
  const float* o_w      = (const float*)d_in[10];
  const float* router_w = (const float*)d_in[11];
  const float* e_gate   = (const float*)d_in[12];
  const float* e_up     = (const float*)d_in[13];
  const float* e_down   = (const float*)d_in[14];
  const float* s_gate   = (const float*)d_in[15];
  const float* s_up     = (const float*)d_in[16];
  const float* s_down   = (const float*)d_in[17];
  const float* sg_w     = (const float*)d_in[18];
  float* out = (float*)d_out;

  char* base = (char*)d_ws;
  size_t off_ = 0;
  auto alc = [&](size_t nbytes) -> char* {
    off_ = (off_ + 255) & ~(size_t)255;
    char* p = base + off_;
    off_ += nbytes;
    return p;
  };
  // transposed bf16 weights
  short* qkvT = (short*)alc((size_t)3072 * H_ * 2);          // rows: q 0..2047, k 2048..2559, v 2560..3071
  short* oT   = (short*)alc((size_t)H_ * H_ * 2);
  short* eguT = (short*)alc((size_t)E_ * 2816 * H_ * 2);     // per expert: gate rows 0..1407, up 1408..2815
  short* edT  = (short*)alc((size_t)E_ * H_ * IM_ * 2);
  short* sguT = (short*)alc((size_t)11264 * H_ * 2);         // gate rows 0..5631, up 5632..11263
  short* sdT  = (short*)alc((size_t)H_ * ISH_ * 2);
  // activations
  short* x1      = (short*)alc((size_t)S_ * H_ * 2);
  float* qkv_f   = (float*)alc((size_t)S_ * 3072 * 4);
  float* ct      = (float*)alc((size_t)S_ * 64 * 4);
  float* st      = (float*)alc((size_t)S_ * 64 * 4);
  short* qr      = (short*)alc((size_t)S_ * H_ * 2);
  short* kr      = (short*)alc((size_t)S_ * 512 * 2);
  short* vt      = (short*)alc((size_t)S_ * 512 * 2);
  float* attn_f  = (float*)alc((size_t)S_ * H_ * 4);
  short* attn    = (short*)alc((size_t)S_ * H_ * 2);
  float* h2      = (float*)alc((size_t)S_ * H_ * 4);
  short* x2      = (short*)alc((size_t)S_ * H_ * 2);
  float* rs2     = (float*)alc(S_ * 4);
  int*   top_i   = (int*)alc(2 * S_ * 4);
  float* top_w   = (float*)alc(2 * S_ * 4);
  float* sg_sig  = (float*)alc(S_ * 4);
  int*   counts  = (int*)alc(64);
  int*   pos     = counts + 8;
  int*   offs    = (int*)alc(32);
  int*   list    = (int*)alc(2 * S_ * 4);
  float* pw      = (float*)alc(2 * S_ * 4);
  char*  region  = alc(100663296);   // 96 MiB overlay
  float* scores  = (float*)region;                            // 64 MiB
  short* P       = (short*)(region + 67108864);               // 32 MiB
  float* g_moeF  = (float*)region;                            // 2048x2816 fp32 = 23 MB
  short* gu_moeB = (short*)(region + 23068672);               // 2048x1408 bf16
  float* gushF   = (float*)(region + 28835840);               // 1024x11264 fp32 = 46 MB
  short* gushB   = (short*)(region + 74973184);               // 1024x5632 bf16

  // 0) weight transpose+convert
  transpose_k<<<dim3(32, 32, 1), 256, 0, stream>>>(q_w, qkvT, H_, H_, 0, 0);
  transpose_k<<<dim3(8, 32, 1), 256, 0, stream>>>(k_w, qkvT + (size_t)2048 * H_, H_, 512, 0, 0);
  transpose_k<<<dim3(8, 32, 1), 256, 0, stream>>>(v_w, qkvT + (size_t)2560 * H_, H_, 512, 0, 0);
  transpose_k<<<dim3(32, 32, 1), 256, 0, stream>>>(o_w, oT, H_, H_, 0, 0);
  transpose_k<<<dim3(22, 32, E_), 256, 0, stream>>>(e_gate, eguT, H_, IM_,
                                                    (long long)H_ * IM_, (long long)2816 * H_);
  transpose_k<<<dim3(22, 32, E_), 256, 0, stream>>>(e_up, eguT + (size_t)1408 * H_, H_, IM_,
                                                    (long long)H_ * IM_, (long long)2816 * H_);
  transpose_k<<<dim3(32, 22, E_), 256, 0, stream>>>(e_down, edT, IM_, H_,
                                                    (long long)IM_ * H_, (long long)IM_ * H_);
  transpose_k<<<dim3(88, 32, 1), 256, 0, stream>>>(s_gate, sguT, H_, ISH_, 0, 0);
  transpose_k<<<dim3(88, 32, 1), 256, 0, stream>>>(s_up, sguT + (size_t)5632 * H_, H_, ISH_, 0, 0);
  transpose_k<<<dim3(32, 88, 1), 256, 0, stream>>>(s_down, sdT, ISH_, H_, 0, 0);

  // 1) rope tables + rmsnorm1; h2 pre-init with residual
  rope_table_k<<<256, 256, 0, stream>>>(pos_ids, ct, st);
  rmsnorm_k<<<S_, 256, 0, stream>>>(hidden, ln1_w, x1, nullptr, nullptr);
  hipMemcpyAsync(h2, hidden, (size_t)S_ * H_ * 4, hipMemcpyDeviceToDevice, stream);
  hipMemsetAsync(attn_f, 0, (size_t)S_ * H_ * 4, stream);

  // 2) fused QKV projection (split-K=2, atomic into bias-initialized buffer)
  bias_init_k<<<12288, 256, 0, stream>>>(q_b, k_b, v_b, qkv_f);
  {
    GemmP p = mkp();
    p.A = x1; p.lda = H_;
    p.B = qkvT; p.ldb = H_;
    p.C = qkv_f; p.ldc = 3072;
    p.M = S_; p.N = 3072; p.K = H_;
    p.ksplit = 2; p.kchunk = 1024;
    gemm_bt<1><<<dim3(8, 24, 2), 256, 0, stream>>>(p);
  }

  // 3) RoPE + V transpose
  rope_apply_k<<<8192, 256, 0, stream>>>(qkv_f, qr, ct, st, 0, 2048, S_ * H_);
  rope_apply_k<<<2048, 256, 0, stream>>>(qkv_f, kr, ct, st, 2048, 512, S_ * 512);
  vtrans_k<<<2048, 256, 0, stream>>>(qkv_f, vt);

  // 4) scores = scale * Q K^T (causal tiles only)
  {
    GemmP p = mkp();
    p.A = qr; p.strideA = HD_; p.lda = H_;
    p.B = kr; p.strideB = HD_; p.bdiv = 4; p.ldb = 512;
    p.C = scores; p.strideC = (long long)S_ * S_; p.ldc = S_;
    p.alpha = 0.08838834764831845f;
    p.M = S_; p.N = S_; p.K = HD_; p.cskip = 1;
    p.kchunk = HD_;
    gemm_bt<0><<<dim3(8, 8, NH_), 256, 0, stream>>>(p);
  }
  softmax_k<<<NH_ * S_, 256, 0, stream>>>(scores, P);
  // 5) attn = P @ V  (split-K=4 over causal K, atomic into zeroed fp32)
  {
    GemmP p = mkp();
    p.A = P; p.strideA = (long long)S_ * S_; p.lda = S_;
    p.B = vt; p.strideB = (long long)HD_ * S_; p.bdiv = 4; p.ldb = S_;
    p.C = attn_f; p.strideC = HD_; p.ldc = H_;
    p.M = S_; p.N = HD_; p.K = S_; p.ckb = 1;
    p.ksplit = 4; p.kchunk = 256;
    gemm_bt<1><<<dim3(8, 1, NH_ * 4), 256, 0, stream>>>(p);
  }
  cvt_bf16_k<<<8192, 256, 0, stream>>>(attn_f, attn, S_ * H_);
  // 6) O-proj + residual -> h2 (pre-initialized with hidden), split-K=4
  {
    GemmP p = mkp();
    p.A = attn; p.lda = H_;
    p.B = oT; p.ldb = H_;
    p.C = h2; p.ldc = H_;
    p.M = S_; p.N = H_; p.K = H_;
    p.ksplit = 4; p.kchunk = 512;
    gemm_bt<1><<<dim3(8, 16, 4), 256, 0, stream>>>(p);
  }

  // 7) rmsnorm2 (x2 bf16; copy h2 -> d_out as accumulator base; save 1/rms)
  rmsnorm_k<<<S_, 256, 0, stream>>>(h2, ln2_w, x2, out, rs2);

  // 8) router / top-2 / gather lists
  hipMemsetAsync(counts, 0, 64, stream);
  router_k<<<S_, 64, 0, stream>>>(h2, rs2, ln2_w, router_w, sg_w, top_i, top_w, sg_sig, counts);
  scan_k<<<1, 1, 0, stream>>>(counts, offs);
  fill_k<<<4, 256, 0, stream>>>(top_i, top_w, offs, pos, list, pw);

  // 9) experts: fused gate+up (gathered, split-K=2), silu, down (scatter, split-K=2)
  hipMemsetAsync(g_moeF, 0, (size_t)2048 * 2816 * 4, stream);
  {
    GemmP p = mkp();
    p.A = x2; p.lda = H_;
    p.B = eguT; p.strideB = (long long)2816 * H_; p.ldb = H_;
    p.C = g_moeF; p.ldc = 2816;
    p.e_off = offs; p.e_cnt = counts; p.list = list;
    p.M = S_; p.N = 2816; p.K = H_;
    p.ksplit = 2; p.kchunk = 1024;
    gemm_bt<3><<<dim3(8, 22, E_ * 2), 256, 0, stream>>>(p);
  }
  silu_mul_k<<<11264, 256, 0, stream>>>(g_moeF, gu_moeB, IM_, 2816, 2048 * IM_);
  {
    GemmP p = mkp();
    p.A = gu_moeB; p.lda = IM_;
    p.B = edT; p.strideB = (long long)H_ * IM_; p.ldb = IM_;
    p.C = out; p.ldc = H_;
    p.e_off = offs; p.e_cnt = counts; p.list = list; p.scale = pw;
    p.M = S_; p.N = H_; p.K = IM_;
    p.ksplit = 2; p.kchunk = 704;
    gemm_bt<4><<<dim3(8, 16, E_ * 2), 256, 0, stream>>>(p);
  }

  // 10) shared expert: fused gate+up (704 blocks, plain store), silu, down (split-K=4)
  {
    GemmP p = mkp();
    p.A = x2; p.lda = H_;
    p.B = sguT; p.ldb = H_;
    p.C = gushF; p.ldc = 11264;
    p.M = S_; p.N = 11264; p.K = H_;
    p.kchunk = H_;
    gemm_bt<0><<<dim3(8, 88, 1), 256, 0, stream>>>(p);
  }
  silu_mul_k<<<22528, 256, 0, stream>>>(gushF, gushB, ISH_, 11264, S_ * ISH_);
  {
    GemmP p = mkp();
    p.A = gushB; p.lda = ISH_;
    p.B = sdT; p.ldb = ISH_;
    p.C = out; p.ldc = H_; p.scale = sg_sig;
    p.M = S_; p.N = H_; p.K = ISH_;
    p.ksplit = 4; p.kchunk = 1408;
    gemm_bt<5><<<dim3(8, 16, 4), 256, 0, stream>>>(p);
  }
}

// Round 6
// 699.049 us; speedup vs baseline: 1.2932x; 1.1964x over previous
//
#include <hip/hip_runtime.h>
#include <hip/hip_bf16.h>

// ---------- constants ----------
#define S_ 1024
#define H_ 2048
#define NH_ 16
#define KVH_ 4
#define HD_ 128
#define IM_ 1408
#define ISH_ 5632
#define E_ 8

typedef __bf16 bf16x8 __attribute__((ext_vector_type(8)));
typedef float f32x4 __attribute__((ext_vector_type(4)));

typedef unsigned int __attribute__((address_space(1))) as1_u32;
typedef unsigned int __attribute__((address_space(3))) as3_u32;

__device__ __forceinline__ void gload16(const void* g, void* l) {
  __builtin_amdgcn_global_load_lds((const as1_u32*)g, (as3_u32*)l, 16, 0, 0);
}

__device__ __forceinline__ short f2bf(float f) {
  unsigned u = __float_as_uint(f);
  u = u + 0x7FFFu + ((u >> 16) & 1u);   // RTNE
  return (short)(u >> 16);
}

__device__ __forceinline__ f32x4 mfma16(bf16x8 a, bf16x8 b, f32x4 c) {
  return __builtin_amdgcn_mfma_f32_16x16x32_bf16(a, b, c, 0, 0, 0);
}

template<bool MAXOP>
__device__ __forceinline__ float block_reduce(float v, float* sbuf) {
  #pragma unroll
  for (int o = 32; o >= 1; o >>= 1) {
    float t = __shfl_down(v, o);
    v = MAXOP ? fmaxf(v, t) : (v + t);
  }
  int lane = threadIdx.x & 63, w = threadIdx.x >> 6;
  if (lane == 0) sbuf[w] = v;
  __syncthreads();
  float r = sbuf[0];
  #pragma unroll
  for (int i = 1; i < 4; i++) r = MAXOP ? fmaxf(r, sbuf[i]) : (r + sbuf[i]);
  __syncthreads();
  return r;
}

// ---------- transpose+convert: src fp32 [z][R][C] -> dst bf16 [z][C][R] ----------
__global__ __launch_bounds__(256) void transpose_k(const float* src, short* dst, int R, int C,
                                                   long long srcZ, long long dstZ) {
  __shared__ short tile[64][72];
  src += (long long)blockIdx.z * srcZ;
  dst += (long long)blockIdx.z * dstZ;
  const int r0 = blockIdx.y * 64, c0 = blockIdx.x * 64;
  const int t = threadIdx.x;
  const int tr = t >> 4, tc4 = (t & 15) * 4;
  #pragma unroll
  for (int i = 0; i < 4; i++) {
    int r = tr + i * 16;
    float4 v = *(const float4*)&src[(size_t)(r0 + r) * C + c0 + tc4];
    tile[tc4 + 0][r] = f2bf(v.x);
    tile[tc4 + 1][r] = f2bf(v.y);
    tile[tc4 + 2][r] = f2bf(v.z);
    tile[tc4 + 3][r] = f2bf(v.w);
  }
  __syncthreads();
  const int row = t >> 2, kc = (t & 3) * 16;
  #pragma unroll
  for (int j = 0; j < 2; j++) {
    int kcol = kc + j * 8;
    *(int4*)&dst[(size_t)(c0 + row) * R + r0 + kcol] = *(const int4*)&tile[row][kcol];
  }
}

// ---------- GEMM: A bf16 [M,K], B bf16 [N,K] (K-contig), 2-phase dbuf, split-K ----------
// grid: x = N-tile (fastest; M-cull lives on y, uncorrelated with XCD=lin%8),
//       y = M-tile, z = zo*ksplit + kchunk-index.
// LDS bank-conflict fix (rule #21 both-sides swizzle): the 16B k-slot within
// each 64B LDS row is XORed with row bits ((row>>1)&3); staging pre-swizzles
// the GLOBAL source column so global_load_lds' linear dest lands data where
// the swizzled ds_read expects it. Same XOR for A and B frags (same li) keeps
// the MFMA k-bijection consistent.
// EPI 0: C fp32 = alpha*acc                          (plain store, ksplit==1 only)
// EPI 1: atomicAdd(C, alpha*acc)                     (split-K dense)
// EPI 3: expert: A row = list[off+m], atomicAdd(C[(off+m)*ldc+n], acc)
// EPI 4: expert: A row = off+m, atomicAdd(C[list[off+m]*ldc+n], scale[off+m]*acc)
// EPI 5: atomicAdd(C[m*ldc+n], scale[m]*acc)
struct GemmP {
  const short* A; long long strideA; int adiv; int lda;
  const short* B; long long strideB; int bdiv; int ldb;
  void* C; long long strideC; int cdiv; int ldc;
  const int* e_off; const int* e_cnt;
  const int* list; const float* scale;
  float alpha;
  int M, N, K;
  int cskip, ckb;
  int ksplit, kchunk;
};

template<int EPI>
__global__ __launch_bounds__(256) void gemm_bt(GemmP p) {
  constexpr int BM = 128, BN = 128, BK = 32;
  __shared__ __align__(16) short As[2][BM * BK];
  __shared__ __align__(16) short Bs[2][BN * BK];
  const int zz = blockIdx.z;
  const int zo = zz / p.ksplit;
  const int kc = zz - zo * p.ksplit;
  const int m0 = blockIdx.y * BM;
  const int n0 = blockIdx.x * BN;
  int off = 0, cnt = p.M;
  if constexpr (EPI == 3 || EPI == 4) {
    off = p.e_off[zo]; cnt = p.e_cnt[zo];
    if (m0 >= cnt) return;
  }
  if (p.cskip && n0 >= m0 + BM) return;
  int kend = p.ckb ? min(m0 + BM, p.K) : p.K;
  const int kbeg = kc * p.kchunk;
  kend = min(kend, kbeg + p.kchunk);
  if (kbeg >= kend) return;

  const short* Ab = p.A + (long long)(zo / p.adiv) * p.strideA;
  const short* Bb = p.B + (long long)(zo / p.bdiv) * p.strideB;

  const int tid = threadIdx.x;
  const int lane = tid & 63, wid = tid >> 6;
  const int wr = wid >> 1, wc = wid & 1;
  const int kg = lane >> 4, li = lane & 15;

  // staging: thread tid fills LDS row (tid>>2)+c*64, 16B slot (tid&3).
  // source k-slot is pre-swizzled: s = (tid&3) ^ ((row>>1)&3), row bits from tid>>3.
  const int srow = tid >> 2;
  const int scol = (((tid & 3) ^ ((tid >> 3) & 3))) * 8;
  const short* aSrc[2];
  const short* bSrc[2];
  #pragma unroll
  for (int c = 0; c < 2; c++) {
    int ra = srow + c * 64;
    int gr;
    if constexpr (EPI == 3)      { int rr = m0 + ra; if (rr >= cnt) rr = cnt - 1; gr = p.list[off + rr]; }
    else if constexpr (EPI == 4) { int rr = m0 + ra; if (rr >= cnt) rr = cnt - 1; gr = off + rr; }
    else                         gr = m0 + ra;
    aSrc[c] = Ab + (long long)gr * p.lda + scol;
    bSrc[c] = Bb + (long long)(n0 + ra) * p.ldb + scol;
  }

  f32x4 acc[4][4];
  #pragma unroll
  for (int i = 0; i < 4; i++)
    #pragma unroll
    for (int j = 0; j < 4; j++) acc[i][j] = (f32x4){0.f, 0.f, 0.f, 0.f};

  // prologue: stage first tile into buf 0
  #pragma unroll
  for (int c = 0; c < 2; c++) {
    gload16(aSrc[c] + kbeg, &As[0][tid * 8 + c * 2048]);
    gload16(bSrc[c] + kbeg, &Bs[0][tid * 8 + c * 2048]);
  }
  __syncthreads();

  // fragment reads use the same swizzled k-slot: kgx = kg ^ ((li>>1)&3)
  const int kgx = kg ^ ((li >> 1) & 3);

  int cur = 0;
  for (int k0 = kbeg; k0 < kend; k0 += BK) {
    // issue next-tile loads into the other buffer
    const int nk = k0 + BK;
    if (nk < kend) {
      #pragma unroll
      for (int c = 0; c < 2; c++) {
        gload16(aSrc[c] + nk, &As[cur ^ 1][tid * 8 + c * 2048]);
        gload16(bSrc[c] + nk, &Bs[cur ^ 1][tid * 8 + c * 2048]);
      }
    }
    bf16x8 av[4], bv[4];
    #pragma unroll
    for (int mi = 0; mi < 4; mi++)
      av[mi] = *(const bf16x8*)&As[cur][(wr * 64 + mi * 16 + li) * BK + kgx * 8];
    #pragma unroll
    for (int nj = 0; nj < 4; nj++)
      bv[nj] = *(const bf16x8*)&Bs[cur][(wc * 64 + nj * 16 + li) * BK + kgx * 8];
    #pragma unroll
    for (int mi = 0; mi < 4; mi++)
      #pragma unroll
      for (int nj = 0; nj < 4; nj++)
        acc[mi][nj] = mfma16(av[mi], bv[nj], acc[mi][nj]);
    __syncthreads();   // drains vmcnt (next tile landed) + orders LDS reuse
    cur ^= 1;
  }

  const long long zc = (long long)(zo / p.cdiv) * p.strideC;
  #pragma unroll
  for (int mi = 0; mi < 4; mi++) {
    #pragma unroll
    for (int nj = 0; nj < 4; nj++) {
      #pragma unroll
      for (int r = 0; r < 4; r++) {
        int ml = wr * 64 + mi * 16 + kg * 4 + r;
        int nl2 = wc * 64 + nj * 16 + li;
        int mg = m0 + ml, ng = n0 + nl2;
        float v = acc[mi][nj][r] * p.alpha;
        if constexpr (EPI == 0) {
          float* C = (float*)p.C + zc;
          C[(long long)mg * p.ldc + ng] = v;
        } else if constexpr (EPI == 1) {
          float* C = (float*)p.C + zc;
          atomicAdd(&C[(long long)mg * p.ldc + ng], v);
        } else if constexpr (EPI == 3) {
          if (mg < cnt) {
            float* C = (float*)p.C;
            atomicAdd(&C[(long long)(off + mg) * p.ldc + ng], v);
          }
        } else if constexpr (EPI == 4) {
          if (mg < cnt) {
            float* C = (float*)p.C;
            int tok = p.list[off + mg];
            atomicAdd(&C[(long long)tok * p.ldc + ng], p.scale[off + mg] * v);
          }
        } else if constexpr (EPI == 5) {
          float* C = (float*)p.C;
          atomicAdd(&C[(long long)mg * p.ldc + ng], p.scale[mg] * v);
        }
      }
    }
  }
}

// ---------- aux kernels ----------
__global__ __launch_bounds__(256) void rope_table_k(const int* pos_ids, float* ct, float* st) {
  int i = blockIdx.x * 256 + threadIdx.x;          // 1024*64
  int p = i >> 6, f = i & 63;
  float pos = (float)pos_ids[p];
  float inv = powf(1.0e6f, -(float)f * (1.f / 64.f));
  float a = pos * inv;
  ct[i] = cosf(a); st[i] = sinf(a);
}

__global__ __launch_bounds__(256) void rmsnorm_k(const float* x, const float* w, short* o,
                                                 float* copy_out, float* rs_out) {
  __shared__ float sbuf[4];
  int t = blockIdx.x;
  const float* xr = x + (long long)t * H_;
  float ss = 0.f;
  for (int i = threadIdx.x; i < H_ / 4; i += 256) {
    float4 v = ((const float4*)xr)[i];
    ss += v.x * v.x + v.y * v.y + v.z * v.z + v.w * v.w;
  }
  ss = block_reduce<false>(ss, sbuf);
  float rs = rsqrtf(ss * (1.f / (float)H_) + 1e-6f);
  for (int i = threadIdx.x; i < H_; i += 256) {
    float xv = xr[i];
    o[(long long)t * H_ + i] = f2bf(xv * rs * w[i]);
    if (copy_out) copy_out[(long long)t * H_ + i] = xv;
  }
  if (rs_out && threadIdx.x == 0) rs_out[t] = rs;
}

__global__ __launch_bounds__(256) void bias_init_k(const float* qb, const float* kb,
                                                   const float* vb, float* qkv) {
  int i = blockIdx.x * 256 + threadIdx.x;          // 1024*3072
  int j = i & 3071;
  float b = (j < 2048) ? qb[j] : ((j < 2560) ? kb[j - 2048] : vb[j - 2560]);
  qkv[i] = b;
}

// RoPE from fused qkv fp32 [t, 3072] slice -> bf16 [t, width]
__global__ __launch_bounds__(256) void rope_apply_k(const float* src, short* dst, const float* ct,
                                                    const float* st, int srcoff, int width, int total) {
  int i = blockIdx.x * 256 + threadIdx.x;
  if (i >= total) return;
  int t = i / width, j = i - t * width;
  int d = j & 127, f = d & 63;
  float c = ct[t * 64 + f], s = st[t * 64 + f];
  const float* row = src + (long long)t * 3072 + srcoff;
  float xv = row[j];
  float ov = (d < 64) ? -row[j + 64] : row[j - 64];
  dst[i] = f2bf(xv * c + ov * s);
}

__global__ __launch_bounds__(256) void vtrans_k(const float* qkv, short* vt) {
  int i = blockIdx.x * 256 + threadIdx.x;          // kvh*131072 + d*1024 + s
  int kvh = i >> 17, rem = i & 131071;
  int d = rem >> 10, s_ = rem & 1023;
  vt[i] = f2bf(qkv[(long long)s_ * 3072 + 2560 + kvh * 128 + d]);
}

__global__ __launch_bounds__(256) void cvt_bf16_k(const float* src, short* dst, int total) {
  int i = blockIdx.x * 256 + threadIdx.x;
  if (i < total) dst[i] = f2bf(src[i]);
}

__global__ __launch_bounds__(256) void softmax_k(const float* sc, short* P) {
  __shared__ float sbuf[4];
  long long row = blockIdx.x;                      // h*1024+q
  int q = (int)(row & (S_ - 1));
  const float* sr = sc + row * S_;
  short* pr = P + row * S_;
  int L = q + 1;
  float mx = -3.4e38f;
  for (int i = threadIdx.x; i < L; i += 256) mx = fmaxf(mx, sr[i]);
  mx = block_reduce<true>(mx, sbuf);
  float s = 0.f;
  for (int i = threadIdx.x; i < L; i += 256) s += __expf(sr[i] - mx);
  s = block_reduce<false>(s, sbuf);
  float inv = 1.f / s;
  for (int i = threadIdx.x; i < S_; i += 256) {
    float pv = (i < L) ? __expf(sr[i] - mx) * inv : 0.f;
    pr[i] = f2bf(pv);
  }
}

__global__ void router_k(const float* h2, const float* rs, const float* w2,
                         const float* rw, const float* sgw,
                         int* top_i, float* top_w, float* sg_sig, int* counts) {
  int t = blockIdx.x;
  int l = threadIdx.x;   // 64 threads
  float le[8] = {0, 0, 0, 0, 0, 0, 0, 0};
  float ls = 0.f;
  float r = rs[t];
  for (int k = l; k < H_; k += 64) {
    float xv = h2[(long long)t * H_ + k] * r * w2[k];
    ls += xv * sgw[k];
    const float* rk = rw + k * E_;
    #pragma unroll
    for (int e = 0; e < E_; e++) le[e] += xv * rk[e];
  }
  #pragma unroll
  for (int o = 32; o >= 1; o >>= 1) {
    ls += __shfl_down(ls, o);
    #pragma unroll
    for (int e = 0; e < E_; e++) le[e] += __shfl_down(le[e], o);
  }
  if (l == 0) {
    float m = le[0];
    for (int e = 1; e < E_; e++) m = fmaxf(m, le[e]);
    float pe[8], s = 0.f;
    for (int e = 0; e < E_; e++) { pe[e] = __expf(le[e] - m); s += pe[e]; }
    float inv = 1.f / s;
    for (int e = 0; e < E_; e++) pe[e] *= inv;
    int i1 = 0;
    for (int e = 1; e < E_; e++) if (pe[e] > pe[i1]) i1 = e;
    int i2 = -1;
    for (int e = 0; e < E_; e++) if (e != i1 && (i2 < 0 || pe[e] > pe[i2])) i2 = e;
    top_i[2 * t] = i1; top_i[2 * t + 1] = i2;
    top_w[2 * t] = pe[i1]; top_w[2 * t + 1] = pe[i2];
    sg_sig[t] = 1.f / (1.f + __expf(-ls));
    atomicAdd(&counts[i1], 1); atomicAdd(&counts[i2], 1);
  }
}

__global__ void scan_k(const int* counts, int* offs) {
  if (threadIdx.x == 0 && blockIdx.x == 0) {
    int s = 0;
    for (int e = 0; e < E_; e++) { offs[e] = s; s += counts[e]; }
  }
}

__global__ __launch_bounds__(256) void fill_k(const int* top_i, const float* top_w, const int* offs,
                                              int* pos, int* list, float* pw) {
  int t = blockIdx.x * 256 + threadIdx.x;
  if (t >= S_) return;
  for (int j = 0; j < 2; j++) {
    int e = top_i[2 * t + j];
    int p_ = atomicAdd(&pos[e], 1);
    int slot = offs[e] + p_;
    list[slot] = t; pw[slot] = top_w[2 * t + j];
  }
}

// fused silu: src fp32 rows of [srcld], g at col j, u at col half+j -> dst bf16 [t*half+j]
__global__ __launch_bounds__(256) void silu_mul_k(const float* src, short* dst, int half,
                                                  int srcld, int total) {
  int i = blockIdx.x * 256 + threadIdx.x;
  if (i >= total) return;
  int t = i / half, j = i - t * half;
  const float* row = src + (long long)t * srcld;
  float g = row[j], u = row[half + j];
  float sig = 1.f / (1.f + __expf(-g));
  dst[i] = f2bf(g * sig * u);
}

// ---------- host ----------
static GemmP mkp() {
  GemmP p{};
  p.adiv = 1; p.bdiv = 1; p.cdiv = 1; p.alpha = 1.f;
  p.ksplit = 1; p.kchunk = 1 << 30;
  return p;
}

extern "C" void kernel_launch(void* const* d_in, const int* in_sizes, int n_in,
                              void* d_out, int out_size, void* d_ws, size_t ws_size,
                              hipStream_t stream) {
  const float* hidden   = (const float*)d_in[0];
  const int*   pos_ids  = (const int*)d_in[1];
  const float* ln1_w    = (const float*)d_in[2];
  const float* ln2_w    = (const float*)d_in[3];
  const float* q_w      = (const float*)d_in[4];
  const float* q_b      = (const float*)d_in[5];
  const float* k_w      = (const float*)d_in[6];
  const float* k_b      = (const float*)d_in[7];
  const float* v_w      = (const float*)d_in[8];
  const float* v_b      = (const float*)d_in[9];
  const float* o_w      = (const float*)d_in[10];
  const float* router_w = (const float*)d_in[11];
  const float* e_gate   = (const float*)d_in[12];
  const float* e_up     = (const float*)d_in[13];
  const float* e_down   = (const float*)d_in[14];
  const float* s_gate   = (const float*)d_in[15];
  const float* s_up     = (const float*)d_in[16];
  const float* s_down   = (const float*)d_in[17];
  const float* sg_w     = (const float*)d_in[18];
  float* out = (float*)d_out;

  char* base = (char*)d_ws;
  size_t off_ = 0;
  auto alc = [&](size_t nbytes) -> char* {
    off_ = (off_ + 255) & ~(size_t)255;
    char* p = base + off_;
    off_ += nbytes;
    return p;
  };
  // transposed bf16 weights
  short* qkvT = (short*)alc((size_t)3072 * H_ * 2);          // rows: q 0..2047, k 2048..2559, v 2560..3071
  short* oT   = (short*)alc((size_t)H_ * H_ * 2);
  short* eguT = (short*)alc((size_t)E_ * 2816 * H_ * 2);     // per expert: gate rows 0..1407, up 1408..2815
  short* edT  = (short*)alc((size_t)E_ * H_ * IM_ * 2);
  short* sguT = (short*)alc((size_t)11264 * H_ * 2);         // gate rows 0..5631, up 5632..11263
  short* sdT  = (short*)alc((size_t)H_ * ISH_ * 2);
  // activations
  short* x1      = (short*)alc((size_t)S_ * H_ * 2);
  float* qkv_f   = (float*)alc((size_t)S_ * 3072 * 4);
  float* ct      = (float*)alc((size_t)S_ * 64 * 4);
  float* st      = (float*)alc((size_t)S_ * 64 * 4);
  short* qr      = (short*)alc((size_t)S_ * H_ * 2);
  short* kr      = (short*)alc((size_t)S_ * 512 * 2);
  short* vt      = (short*)alc((size_t)S_ * 512 * 2);
  float* attn_f  = (float*)alc((size_t)S_ * H_ * 4);
  short* attn    = (short*)alc((size_t)S_ * H_ * 2);
  float* h2      = (float*)alc((size_t)S_ * H_ * 4);
  short* x2      = (short*)alc((size_t)S_ * H_ * 2);
  float* rs2     = (float*)alc(S_ * 4);
  int*   top_i   = (int*)alc(2 * S_ * 4);
  float* top_w   = (float*)alc(2 * S_ * 4);
  float* sg_sig  = (float*)alc(S_ * 4);
  int*   counts  = (int*)alc(64);
  int*   pos     = counts + 8;
  int*   offs    = (int*)alc(32);
  int*   list    = (int*)alc(2 * S_ * 4);
  float* pw      = (float*)alc(2 * S_ * 4);
  char*  region  = alc(100663296);   // 96 MiB overlay
  float* scores  = (float*)region;                            // 64 MiB
  short* P       = (short*)(region + 67108864);               // 32 MiB
  float* g_moeF  = (float*)region;                            // 2048x2816 fp32 = 23 MB
  short* gu_moeB = (short*)(region + 23068672);               // 2048x1408 bf16
  float* gushF   = (float*)(region + 28835840);               // 1024x11264 fp32 = 46 MB
  short* gushB   = (short*)(region + 74973184);               // 1024x5632 bf16

  // 0) weight transpose+convert
  transpose_k<<<dim3(32, 32, 1), 256, 0, stream>>>(q_w, qkvT, H_, H_, 0, 0);
  transpose_k<<<dim3(8, 32, 1), 256, 0, stream>>>(k_w, qkvT + (size_t)2048 * H_, H_, 512, 0, 0);
  transpose_k<<<dim3(8, 32, 1), 256, 0, stream>>>(v_w, qkvT + (size_t)2560 * H_, H_, 512, 0, 0);
  transpose_k<<<dim3(32, 32, 1), 256, 0, stream>>>(o_w, oT, H_, H_, 0, 0);
  transpose_k<<<dim3(22, 32, E_), 256, 0, stream>>>(e_gate, eguT, H_, IM_,
                                                    (long long)H_ * IM_, (long long)2816 * H_);
  transpose_k<<<dim3(22, 32, E_), 256, 0, stream>>>(e_up, eguT + (size_t)1408 * H_, H_, IM_,
                                                    (long long)H_ * IM_, (long long)2816 * H_);
  transpose_k<<<dim3(32, 22, E_), 256, 0, stream>>>(e_down, edT, IM_, H_,
                                                    (long long)IM_ * H_, (long long)IM_ * H_);
  transpose_k<<<dim3(88, 32, 1), 256, 0, stream>>>(s_gate, sguT, H_, ISH_, 0, 0);
  transpose_k<<<dim3(88, 32, 1), 256, 0, stream>>>(s_up, sguT + (size_t)5632 * H_, H_, ISH_, 0, 0);
  transpose_k<<<dim3(32, 88, 1), 256, 0, stream>>>(s_down, sdT, ISH_, H_, 0, 0);

  // 1) rope tables + rmsnorm1; h2 pre-init with residual
  rope_table_k<<<256, 256, 0, stream>>>(pos_ids, ct, st);
  rmsnorm_k<<<S_, 256, 0, stream>>>(hidden, ln1_w, x1, nullptr, nullptr);
  hipMemcpyAsync(h2, hidden, (size_t)S_ * H_ * 4, hipMemcpyDeviceToDevice, stream);
  hipMemsetAsync(attn_f, 0, (size_t)S_ * H_ * 4, stream);

  // 2) fused QKV projection (split-K=2, atomic into bias-initialized buffer)
  bias_init_k<<<12288, 256, 0, stream>>>(q_b, k_b, v_b, qkv_f);
  {
    GemmP p = mkp();
    p.A = x1; p.lda = H_;
    p.B = qkvT; p.ldb = H_;
    p.C = qkv_f; p.ldc = 3072;
    p.M = S_; p.N = 3072; p.K = H_;
    p.ksplit = 2; p.kchunk = 1024;
    gemm_bt<1><<<dim3(24, 8, 2), 256, 0, stream>>>(p);
  }

  // 3) RoPE + V transpose
  rope_apply_k<<<8192, 256, 0, stream>>>(qkv_f, qr, ct, st, 0, 2048, S_ * H_);
  rope_apply_k<<<2048, 256, 0, stream>>>(qkv_f, kr, ct, st, 2048, 512, S_ * 512);
  vtrans_k<<<2048, 256, 0, stream>>>(qkv_f, vt);

  // 4) scores = scale * Q K^T (causal tiles only)
  {
    GemmP p = mkp();
    p.A = qr; p.strideA = HD_; p.lda = H_;
    p.B = kr; p.strideB = HD_; p.bdiv = 4; p.ldb = 512;
    p.C = scores; p.strideC = (long long)S_ * S_; p.ldc = S_;
    p.alpha = 0.08838834764831845f;
    p.M = S_; p.N = S_; p.K = HD_; p.cskip = 1;
    p.kchunk = HD_;
    gemm_bt<0><<<dim3(8, 8, NH_), 256, 0, stream>>>(p);
  }
  softmax_k<<<NH_ * S_, 256, 0, stream>>>(scores, P);
  // 5) attn = P @ V  (split-K=4 over causal K, atomic into zeroed fp32)
  {
    GemmP p = mkp();
    p.A = P; p.strideA = (long long)S_ * S_; p.lda = S_;
    p.B = vt; p.strideB = (long long)HD_ * S_; p.bdiv = 4; p.ldb = S_;
    p.C = attn_f; p.strideC = HD_; p.ldc = H_;
    p.M = S_; p.N = HD_; p.K = S_; p.ckb = 1;
    p.ksplit = 4; p.kchunk = 256;
    gemm_bt<1><<<dim3(1, 8, NH_ * 4), 256, 0, stream>>>(p);
  }
  cvt_bf16_k<<<8192, 256, 0, stream>>>(attn_f, attn, S_ * H_);
  // 6) O-proj + residual -> h2 (pre-initialized with hidden), split-K=4
  {
    GemmP p = mkp();
    p.A = attn; p.lda = H_;
    p.B = oT; p.ldb = H_;
    p.C = h2; p.ldc = H_;
    p.M = S_; p.N = H_; p.K = H_;
    p.ksplit = 4; p.kchunk = 512;
    gemm_bt<1><<<dim3(16, 8, 4), 256, 0, stream>>>(p);
  }

  // 7) rmsnorm2 (x2 bf16; copy h2 -> d_out as accumulator base; save 1/rms)
  rmsnorm_k<<<S_, 256, 0, stream>>>(h2, ln2_w, x2, out, rs2);

  // 8) router / top-2 / gather lists
  hipMemsetAsync(counts, 0, 64, stream);
  router_k<<<S_, 64, 0, stream>>>(h2, rs2, ln2_w, router_w, sg_w, top_i, top_w, sg_sig, counts);
  scan_k<<<1, 1, 0, stream>>>(counts, offs);
  fill_k<<<4, 256, 0, stream>>>(top_i, top_w, offs, pos, list, pw);

  // 9) experts: fused gate+up (gathered, split-K=2), silu, down (scatter, split-K=2)
  hipMemsetAsync(g_moeF, 0, (size_t)2048 * 2816 * 4, stream);
  {
    GemmP p = mkp();
    p.A = x2; p.lda = H_;
    p.B = eguT; p.strideB = (long long)2816 * H_; p.ldb = H_;
    p.C = g_moeF; p.ldc = 2816;
    p.e_off = offs; p.e_cnt = counts; p.list = list;
    p.M = S_; p.N = 2816; p.K = H_;
    p.ksplit = 2; p.kchunk = 1024;
    gemm_bt<3><<<dim3(22, 8, E_ * 2), 256, 0, stream>>>(p);
  }
  silu_mul_k<<<11264, 256, 0, stream>>>(g_moeF, gu_moeB, IM_, 2816, 2048 * IM_);
  {
    GemmP p = mkp();
    p.A = gu_moeB; p.lda = IM_;
    p.B = edT; p.strideB = (long long)H_ * IM_; p.ldb = IM_;
    p.C = out; p.ldc = H_;
    p.e_off = offs; p.e_cnt = counts; p.list = list; p.scale = pw;
    p.M = S_; p.N = H_; p.K = IM_;
    p.ksplit = 2; p.kchunk = 704;
    gemm_bt<4><<<dim3(16, 8, E_ * 2), 256, 0, stream>>>(p);
  }

  // 10) shared expert: fused gate+up (704 blocks, plain store), silu, down (split-K=4)
  {
    GemmP p = mkp();
    p.A = x2; p.lda = H_;
    p.B = sguT; p.ldb = H_;
    p.C = gushF; p.ldc = 11264;
    p.M = S_; p.N = 11264; p.K = H_;
    p.kchunk = H_;
    gemm_bt<0><<<dim3(88, 8, 1), 256, 0, stream>>>(p);
  }
  silu_mul_k<<<22528, 256, 0, stream>>>(gushF, gushB, ISH_, 11264, S_ * ISH_);
  {
    GemmP p = mkp();
    p.A = gushB; p.lda = ISH_;
    p.B = sdT; p.ldb = ISH_;
    p.C = out; p.ldc = H_; p.scale = sg_sig;
    p.M = S_; p.N = H_; p.K = ISH_;
    p.ksplit = 4; p.kchunk = 1408;
    gemm_bt<5><<<dim3(16, 8, 4), 256, 0, stream>>>(p);
  }
}